// Round 4
// baseline (1786.180 us; speedup 1.0000x reference)
//
#include <hip/hip_runtime.h>
#include <cstdint>
#include <cfloat>

// ---------------------------------------------------------------------------
// SimpleVQVAEEncoder, round 4: barrier-free direct-global implicit GEMM.
// lane = pixel. A: per-lane global loads (vmcnt domain, register double-buffer,
// padded z1 => no masks in conv2). Weights: s_load (sole lgkmcnt user) with
// SGPR operand into v_fmac. No LDS, no __syncthreads in any conv K-loop.
// VQ: fused distance+argmin+one-hot (intra-block merge).
// ---------------------------------------------------------------------------

constexpr int B_    = 128;
constexpr int HW3   = 169;
constexpr int NPIXT = B_ * HW3;        // 21632
constexpr int NEMB  = 512;
constexpr int EMB   = 64;

// transpose weights [OC][K] -> [K][OC]
__global__ __launch_bounds__(256) void wtrans_kernel(
    const float* __restrict__ w, float* __restrict__ wt, int OC, int K)
{
    int idx = blockIdx.x * 256 + threadIdx.x;
    if (idx >= OC * K) return;
    int oc = idx / K, k = idx - oc * K;
    wt[(size_t)k * OC + oc] = w[idx];
}

// zero the 2-wide borders of z1p [128*64][52][52]
__global__ __launch_bounds__(256) void border_zero(float* __restrict__ z1p)
{
    int pid = blockIdx.x * 256 + threadIdx.x;      // 128*64*2704 total
    int yx = pid % 2704;
    int y = yx / 52, x = yx - y * 52;
    if (y < 2 || y >= 50 || x < 2 || x >= 50) z1p[pid] = 0.f;
}

template<int IC, int OC, int KH, int KW, int IH, int IW, int IWP, int ICSTR,
         int OH, int OW, int STRIDE, int PAD, bool MASK, bool RELU,
         int OMODE, int OROW, int OPLN, int KSPL, int OCSPL>
__global__ __launch_bounds__(256, 4) void conv_direct(
    const float* __restrict__ in,      // pre-offset if padded layout
    const float* __restrict__ wt,      // [K][OC]
    const float* __restrict__ bias,
    float* __restrict__ out)           // pre-offset for OMODE 0 padded writes
{
    constexpr int K   = IC * KH * KW;
    constexpr int BK  = 32;
    constexpr int KQ  = K / KSPL;
    constexpr int NT  = KQ / BK;                  // 6 / 72 / 16 (all even)
    constexpr int OCQ = OC / OCSPL;
    constexpr int NOC = OCQ / 4;                  // 16 everywhere
    constexpr int HWo = OH * OW;

    const int tid  = threadIdx.x;
    const int lane = tid & 63;
    const int g    = __builtin_amdgcn_readfirstlane(tid >> 6);

    int bx = blockIdx.x;
    int ks = 0, ocs = 0;
    if (KSPL  > 1) { ks  = bx % KSPL;  bx /= KSPL;  }
    if (OCSPL > 1) { ocs = bx % OCSPL; bx /= OCSPL; }
    const int pg    = bx;
    const int oc0   = ocs * OCQ + g * NOC;
    const int kbase = ks * KQ;

    const int pix  = pg * 64 + lane;
    const int n    = pix / HWo;
    const int hw   = pix - n * HWo;
    const int oy   = hw / OW;
    const int ox   = hw - oy * OW;
    const int row0 = oy * STRIDE - PAD;
    const int col0 = ox * STRIDE - PAD;
    const int voff = n * (IC * ICSTR) + row0 * IWP + col0;   // per-lane, loop-invariant

    float acc[NOC];
#pragma unroll
    for (int j = 0; j < NOC; j++) acc[j] = 0.f;

    auto ld = [&](int t, float* pv) {
        const int k0 = kbase + t * BK;
#pragma unroll
        for (int e = 0; e < BK; e++) {
            int k   = k0 + e;                      // uniform -> SALU decompose
            int ic  = k / (KH * KW);
            int r   = k - ic * (KH * KW);
            int ky  = r / KW;
            int kx  = r - ky * KW;
            int off = ic * ICSTR + ky * IWP + kx;
            if (MASK) {
                int iy = row0 + ky, ix = col0 + kx;
                bool v = (((unsigned)iy < (unsigned)IH) & ((unsigned)ix < (unsigned)IW));
                int  a = v ? (voff + off) : 0;
                float x = in[a];
                pv[e] = v ? x : 0.f;
            } else {
                pv[e] = in[voff + off];
            }
        }
    };
    auto fmab = [&](int t, const float* pv) {
        const float* bp = wt + (size_t)(kbase + t * BK) * OC + oc0;  // uniform
#pragma unroll
        for (int kk = 0; kk < BK; kk++) {
            float av = pv[kk];
#pragma unroll
            for (int j = 0; j < NOC; j++)
                acc[j] = fmaf(av, bp[kk * OC + j], acc[j]);   // SGPR weight operand
        }
    };

    float pva[BK], pvb[BK];
    ld(0, pva);
    for (int t = 0; t < NT; t += 2) {
        ld(t + 1, pvb);
        fmab(t, pva);
        if (t + 2 < NT) ld(t + 2, pva);
        fmab(t + 1, pvb);
    }

    if (OMODE == 1) {                              // raw K-partials [ks][oc][pix]
#pragma unroll
        for (int j = 0; j < NOC; j++)
            out[((size_t)ks * OC + oc0 + j) * NPIXT + pix] = acc[j];
    } else {                                       // NCHW (possibly padded rows)
#pragma unroll
        for (int j = 0; j < NOC; j++) {
            int oc  = oc0 + j;
            float v = acc[j] + bias[oc];
            if (RELU) v = fmaxf(v, 0.f);
            out[(size_t)(n * OC + oc) * OPLN + oy * OROW + ox] = v;
        }
    }
}

// ---------------------------------------------------------------------------
// Fused VQ: z = sum of 4 conv3 K-partials + b3 (fixed order, deterministic);
// each of 4 waves scans 128 codes for the block's 64 pixels; LDS merge;
// one-hot written directly (out pre-zeroed). Codebook via wave-uniform s_load.
// ---------------------------------------------------------------------------
__global__ __launch_bounds__(256) void vq_fused(
    const float* __restrict__ zp,           // [4][64][21632]
    const float* __restrict__ b3,           // [64]
    const float* __restrict__ cb,           // [512][64]
    float* __restrict__ out)                // [128][512][169], pre-zeroed
{
    __shared__ float c2s[NEMB];
    __shared__ unsigned long long sh[4][64];

    const int tid  = threadIdx.x;
    const int lane = tid & 63;
    const int wv   = __builtin_amdgcn_readfirstlane(tid >> 6);
    const int p    = blockIdx.x * 64 + lane;       // 338*64 == 21632

#pragma unroll
    for (int i = 0; i < 2; i++) {
        int code = i * 256 + tid;
        const float* c = cb + (size_t)code * EMB;
        float s = 0.f;
#pragma unroll
        for (int j = 0; j < EMB; j += 4) {
            float4 v = *(const float4*)(c + j);
            s = fmaf(v.x, v.x, s); s = fmaf(v.y, v.y, s);
            s = fmaf(v.z, v.z, s); s = fmaf(v.w, v.w, s);
        }
        c2s[code] = s;
    }
    __syncthreads();

    constexpr size_t PSTR = (size_t)EMB * NPIXT;
    float zr[EMB];
    float zz = 0.f;
#pragma unroll
    for (int j = 0; j < EMB; j++) {
        size_t o = (size_t)j * NPIXT + p;
        float v = (zp[o] + zp[PSTR + o]) + (zp[2 * PSTR + o] + zp[3 * PSTR + o]);
        v += b3[j];
        zr[j] = v;
        zz = fmaf(v, v, zz);
    }

    float bestScore = FLT_MAX;
    int   bestIdx   = 0x7fffffff;
    const int base = wv * 128;
    for (int ci = 0; ci < 128; ci++) {
        int code = base + ci;                      // uniform
        const float* c = cb + (size_t)code * EMB;
        float dot = 0.f;
#pragma unroll
        for (int j = 0; j < EMB; j++) dot = fmaf(zr[j], c[j], dot);
        float score = fmaf(-2.f, dot, zz) + c2s[code];
        if (score < bestScore) { bestScore = score; bestIdx = code; }
    }

    unsigned u = __float_as_uint(bestScore);
    u = (bestScore < 0.f) ? ~u : (u | 0x80000000u);
    sh[wv][lane] = ((unsigned long long)u << 32) | (unsigned)bestIdx;
    __syncthreads();

    if (tid < 64) {
        unsigned long long m = sh[0][lane];
        unsigned long long m1 = sh[1][lane]; if (m1 < m) m = m1;
        unsigned long long m2 = sh[2][lane]; if (m2 < m) m = m2;
        unsigned long long m3 = sh[3][lane]; if (m3 < m) m = m3;
        int code = (int)(unsigned)(m & 0xffffffffu);
        int n  = p / HW3;
        int hw = p - n * HW3;
        out[((size_t)n * NEMB + code) * HW3 + hw] = 1.0f;
    }
}

extern "C" void kernel_launch(void* const* d_in, const int* in_sizes, int n_in,
                              void* d_out, int out_size, void* d_ws, size_t ws_size,
                              hipStream_t stream) {
    const float* x  = (const float*)d_in[0];
    const float* w1 = (const float*)d_in[1];
    const float* b1 = (const float*)d_in[2];
    const float* w2 = (const float*)d_in[3];
    const float* b2 = (const float*)d_in[4];
    const float* w3 = (const float*)d_in[5];
    const float* b3 = (const float*)d_in[6];
    const float* cb = (const float*)d_in[7];
    float* out = (float*)d_out;

    // workspace (floats): z1p padded 52x52 | z2 | z3 partials | weightT x3
    float* z1p = (float*)d_ws;                       // 128*64*52*52 = 22151168
    float* z2  = z1p + (size_t)22151168;             // 128*128*16*16 = 4194304
    float* z3p = z2  + (size_t)4194304;              // 4*64*21632    = 5537792
    float* w1t = z3p + (size_t)5537792;              // 192*64
    float* w2t = w1t + 12288;                        // 2304*128
    float* w3t = w2t + 294912;                       // 2048*64
    // total ~129 MB

    hipMemsetAsync(out, 0, (size_t)out_size * sizeof(float), stream);
    border_zero<<<(22151168 + 255) / 256, 256, 0, stream>>>(z1p);

    wtrans_kernel<<<(64 * 192 + 255) / 256, 256, 0, stream>>>(w1, w1t, 64, 192);
    wtrans_kernel<<<(128 * 2304 + 255) / 256, 256, 0, stream>>>(w2, w2t, 128, 2304);
    wtrans_kernel<<<(64 * 2048 + 255) / 256, 256, 0, stream>>>(w3, w3t, 64, 2048);

    // conv1: x [3][192][192] (masked), out -> z1p interior (row stride 52)
    conv_direct<3, 64, 8, 8, 192, 192, 192, 36864,
                48, 48, 4, 2, true, true, 0, 52, 2704, 1, 1>
        <<<4608, 256, 0, stream>>>(x, w1t, b1, z1p + 2 * 52 + 2);
    // conv2: z1p padded (maskless), OC-split 2 -> 1024 blocks
    conv_direct<64, 128, 6, 6, 48, 48, 52, 2704,
                16, 16, 3, 2, false, true, 0, 16, 256, 1, 2>
        <<<1024, 256, 0, stream>>>(z1p + 2 * 52 + 2, w2t, b2, z2);
    // conv3: z2 (pad 0, maskless), K-split 4 -> 1352 blocks, raw partials
    conv_direct<128, 64, 4, 4, 16, 16, 16, 256,
                13, 13, 1, 0, false, false, 1, 0, 0, 4, 1>
        <<<1352, 256, 0, stream>>>(z2, w3t, nullptr, z3p);

    vq_fused<<<338, 256, 0, stream>>>(z3p, b3, cb, out);
}

// Round 6
// 981.975 us; speedup vs baseline: 1.8190x; 1.8190x over previous
//
#include <hip/hip_runtime.h>
#include <cstdint>
#include <cfloat>

// ---------------------------------------------------------------------------
// SimpleVQVAEEncoder, round 6: bf16x3 (3-term split) MFMA convs, 6 products.
// x = h1+h2+h3+e (|e|<=2^-24|x|); C ~= h1h1'+h1h2'+h2h1'+h2h2'+h1h3'+h3h1'
// -> per-product err ~3e-7 (fp32-grade). No LDS, no barriers in convs: each
// lane builds its A-frag from global (k-contiguous by layout choice).
//   conv1: x NCHW fp32, k-order (ic,ky,kx) -> kx-contiguous, masked loads.
//   conv2: z1 NHWC fp32 (conv1 output), k-order (ky,kx,ic) -> ic-contiguous,
//          in-register split; row/col mask per (ky,kx) group.
//   conv3: z2 NHWC bf16x3 (pre-split in conv2 epilogue), maskless; K-split 4
//          -> fp32 partials, summed deterministically in vq_fused (r4-verified).
// mfma_f32_16x16x32_bf16: A[m=lane&15][k=quad*8+j]; B[n=lane&15][k=quad*8+j];
// C/D col=lane&15, row=quad*4+reg.
// ---------------------------------------------------------------------------

constexpr int B_    = 128;
constexpr int HW3   = 169;
constexpr int NPIXT = B_ * HW3;        // 21632
constexpr int NEMB  = 512;
constexpr int EMB   = 64;

typedef __attribute__((ext_vector_type(8))) short short8;
typedef __attribute__((ext_vector_type(4))) float floatx4;

__device__ inline unsigned short brne(float x) {
    unsigned u = __float_as_uint(x);
    return (unsigned short)((u + 0x7fffu + ((u >> 16) & 1u)) >> 16);
}
__device__ inline void bsplit3(float x, unsigned short& a, unsigned short& b,
                               unsigned short& c) {
    a = brne(x);
    float r = x - __uint_as_float(((unsigned)a) << 16);
    b = brne(r);
    float r2 = r - __uint_as_float(((unsigned)b) << 16);
    c = brne(r2);
}

#define MFMA6(acc, a1, a2, a3, b1v, b2v, b3v)                                   \
    acc = __builtin_amdgcn_mfma_f32_16x16x32_bf16(a1, b3v, acc, 0, 0, 0);       \
    acc = __builtin_amdgcn_mfma_f32_16x16x32_bf16(a3, b1v, acc, 0, 0, 0);       \
    acc = __builtin_amdgcn_mfma_f32_16x16x32_bf16(a2, b2v, acc, 0, 0, 0);       \
    acc = __builtin_amdgcn_mfma_f32_16x16x32_bf16(a1, b2v, acc, 0, 0, 0);       \
    acc = __builtin_amdgcn_mfma_f32_16x16x32_bf16(a2, b1v, acc, 0, 0, 0);       \
    acc = __builtin_amdgcn_mfma_f32_16x16x32_bf16(a1, b1v, acc, 0, 0, 0);

// split weights into 3 bf16 planes; reord=0: k=(ic,ky,kx) natural,
// reord=1: k=(ky,kx,ic).
__global__ __launch_bounds__(256) void wsplit(
    const float* __restrict__ w, unsigned short* __restrict__ p1,
    unsigned short* __restrict__ p2, unsigned short* __restrict__ p3,
    int OC, int IC, int KH, int KW, int reord)
{
    int K = IC * KH * KW;
    int idx = blockIdx.x * 256 + threadIdx.x;
    if (idx >= OC * K) return;
    int oc = idx / K, kp = idx - oc * K;
    int src;
    if (reord) {
        int ic = kp % IC;
        int e  = kp / IC;
        int ky = e / KW, kx = e - ky * KW;
        src = ((oc * IC + ic) * KH + ky) * KW + kx;
    } else {
        src = idx;
    }
    unsigned short s1, s2, s3;
    bsplit3(w[src], s1, s2, s3);
    p1[idx] = s1; p2[idx] = s2; p3[idx] = s3;
}

// ---- conv1: 3->64, 8x8, s4, p2. out: z1 fp32 NHWC [128][48][48][64] --------
__global__ __launch_bounds__(256) void conv1_mfma(
    const float* __restrict__ x,
    const unsigned short* __restrict__ wa, const unsigned short* __restrict__ wb,
    const unsigned short* __restrict__ wc,
    const float* __restrict__ bias, float* __restrict__ z1)
{
    const int tid = threadIdx.x, lane = tid & 63;
    const int wv = tid >> 6, col = lane & 15, quad = lane >> 4;
    const int bm = blockIdx.x;
    const int apix = bm * 64 + wv * 16 + col;
    const int n = apix / 2304, hw = apix - n * 2304;
    const int oy = hw / 48, ox = hw - oy * 48;
    const int row0 = oy * 4 - 2, col0 = ox * 4 - 2;
    const int nbase = n * 110592;

    floatx4 acc[4];
#pragma unroll
    for (int nt = 0; nt < 4; nt++) acc[nt] = floatx4{0.f, 0.f, 0.f, 0.f};

    for (int c = 0; c < 3; c++) {                  // ic
        const int cofs = nbase + c * 36864;
#pragma unroll
        for (int kst = 0; kst < 2; kst++) {
            int ky = kst * 4 + quad;
            int iy = row0 + ky;
            bool vy = (unsigned)iy < 192u;
            float f[8];
#pragma unroll
            for (int j = 0; j < 8; j++) {
                int ix = col0 + j;
                bool v = vy & ((unsigned)ix < 192u);
                int a = v ? (cofs + iy * 192 + ix) : 0;
                float t = x[a];
                f[j] = v ? t : 0.f;
            }
            short8 a1, a2, a3;
#pragma unroll
            for (int j = 0; j < 8; j++) {
                unsigned short s1, s2, s3;
                bsplit3(f[j], s1, s2, s3);
                a1[j] = (short)s1; a2[j] = (short)s2; a3[j] = (short)s3;
            }
            const int kf = c * 64 + kst * 32 + quad * 8;
#pragma unroll
            for (int nt = 0; nt < 4; nt++) {
                int wo = (nt * 16 + col) * 192 + kf;
                short8 b1v = *(const short8*)&wa[wo];
                short8 b2v = *(const short8*)&wb[wo];
                short8 b3v = *(const short8*)&wc[wo];
                MFMA6(acc[nt], a1, a2, a3, b1v, b2v, b3v);
            }
        }
    }

#pragma unroll
    for (int reg = 0; reg < 4; reg++) {
        int pix = bm * 64 + wv * 16 + quad * 4 + reg;
        int pn = pix / 2304, phw = pix - pn * 2304;
        int poy = phw / 48, pox = phw - poy * 48;
        int obase = ((pn * 48 + poy) * 48 + pox) * 64;
#pragma unroll
        for (int nt = 0; nt < 4; nt++) {
            int oc = nt * 16 + col;
            float v = acc[nt][reg] + bias[oc];
            z1[obase + oc] = fmaxf(v, 0.f);
        }
    }
}

// ---- conv2: 64->128, 6x6, s3, p2. in: z1 NHWC fp32; out: z2 bf16x3 NHWC ----
__global__ __launch_bounds__(256) void conv2_mfma(
    const float* __restrict__ z1,
    const unsigned short* __restrict__ wa, const unsigned short* __restrict__ wb,
    const unsigned short* __restrict__ wc,
    const float* __restrict__ bias,
    unsigned short* __restrict__ za, unsigned short* __restrict__ zb,
    unsigned short* __restrict__ zc)
{
    const int tid = threadIdx.x, lane = tid & 63;
    const int wv = tid >> 6, col = lane & 15, quad = lane >> 4;
    const int bm = blockIdx.x;
    const int apix = bm * 64 + wv * 16 + col;
    const int n = apix >> 8, hw = apix & 255;
    const int oy = hw >> 4, ox = hw & 15;
    const int row0 = oy * 3 - 2, col0 = ox * 3 - 2;

    floatx4 acc[8];
#pragma unroll
    for (int nt = 0; nt < 8; nt++) acc[nt] = floatx4{0.f, 0.f, 0.f, 0.f};

    for (int g = 0; g < 36; g++) {                 // (ky,kx) groups
        int ky = g / 6, kx = g - ky * 6;
        int iy = row0 + ky, ix = col0 + kx;
        bool valid = ((unsigned)iy < 48u) & ((unsigned)ix < 48u);
        int base = valid ? (((n * 48 + iy) * 48 + ix) << 6) : 0;
#pragma unroll
        for (int kst = 0; kst < 2; kst++) {
            int ic0 = kst * 32 + quad * 8;
            float4 u0 = *(const float4*)&z1[base + ic0];
            float4 u1 = *(const float4*)&z1[base + ic0 + 4];
            float f[8] = {u0.x, u0.y, u0.z, u0.w, u1.x, u1.y, u1.z, u1.w};
#pragma unroll
            for (int j = 0; j < 8; j++) f[j] = valid ? f[j] : 0.f;
            short8 a1, a2, a3;
#pragma unroll
            for (int j = 0; j < 8; j++) {
                unsigned short s1, s2, s3;
                bsplit3(f[j], s1, s2, s3);
                a1[j] = (short)s1; a2[j] = (short)s2; a3[j] = (short)s3;
            }
            const int kf = g * 64 + ic0;
#pragma unroll
            for (int nt = 0; nt < 8; nt++) {
                int wo = (nt * 16 + col) * 2304 + kf;
                short8 b1v = *(const short8*)&wa[wo];
                short8 b2v = *(const short8*)&wb[wo];
                short8 b3v = *(const short8*)&wc[wo];
                MFMA6(acc[nt], a1, a2, a3, b1v, b2v, b3v);
            }
        }
    }

#pragma unroll
    for (int reg = 0; reg < 4; reg++) {
        int pix = bm * 64 + wv * 16 + quad * 4 + reg;
        int obase = pix * 128;                     // NHWC == pixel-major
#pragma unroll
        for (int nt = 0; nt < 8; nt++) {
            int oc = nt * 16 + col;
            float v = fmaxf(acc[nt][reg] + bias[oc], 0.f);
            unsigned short s1, s2, s3;
            bsplit3(v, s1, s2, s3);
            za[obase + oc] = s1; zb[obase + oc] = s2; zc[obase + oc] = s3;
        }
    }
}

// ---- conv3: 128->64, 4x4, s1, p0. in: z2 bf16x3 NHWC; out: fp32 K-partials -
__global__ __launch_bounds__(256) void conv3_mfma(
    const unsigned short* __restrict__ za, const unsigned short* __restrict__ zb,
    const unsigned short* __restrict__ zc,
    const unsigned short* __restrict__ wa, const unsigned short* __restrict__ wb,
    const unsigned short* __restrict__ wc,
    float* __restrict__ z3p)                       // [4][64][21632]
{
    const int tid = threadIdx.x, lane = tid & 63;
    const int wv = tid >> 6, col = lane & 15, quad = lane >> 4;
    const int ks = blockIdx.x & 3, bm = blockIdx.x >> 2;
    const int apix = bm * 64 + wv * 16 + col;
    const int n = apix / 169, hw = apix - n * 169;
    const int oy = hw / 13, ox = hw - oy * 13;

    floatx4 acc[4];
#pragma unroll
    for (int nt = 0; nt < 4; nt++) acc[nt] = floatx4{0.f, 0.f, 0.f, 0.f};

#pragma unroll
    for (int gg = 0; gg < 4; gg++) {
        int g = ks * 4 + gg;                       // (ky,kx) group
        int ky = g >> 2, kx = g & 3;
        int base = ((n * 16 + oy + ky) * 16 + ox + kx) << 7;
#pragma unroll
        for (int hh = 0; hh < 2; hh++) {
#pragma unroll
            for (int kst = 0; kst < 2; kst++) {
                int ic0 = hh * 64 + kst * 32 + quad * 8;
                short8 a1 = *(const short8*)&za[base + ic0];
                short8 a2 = *(const short8*)&zb[base + ic0];
                short8 a3 = *(const short8*)&zc[base + ic0];
                const int kf = g * 128 + ic0;
#pragma unroll
                for (int nt = 0; nt < 4; nt++) {
                    int wo = (nt * 16 + col) * 2048 + kf;
                    short8 b1v = *(const short8*)&wa[wo];
                    short8 b2v = *(const short8*)&wb[wo];
                    short8 b3v = *(const short8*)&wc[wo];
                    MFMA6(acc[nt], a1, a2, a3, b1v, b2v, b3v);
                }
            }
        }
    }

#pragma unroll
    for (int reg = 0; reg < 4; reg++) {
        int pix = bm * 64 + wv * 16 + quad * 4 + reg;
#pragma unroll
        for (int nt = 0; nt < 4; nt++) {
            int oc = nt * 16 + col;
            z3p[((size_t)(ks * 64 + oc)) * NPIXT + pix] = acc[nt][reg];
        }
    }
}

// ---------------------------------------------------------------------------
// Fused VQ (verified round 4): z = sum of 4 conv3 K-partials + b3;
// 4 waves x 128 codes each; LDS merge; one-hot write (out pre-zeroed).
// ---------------------------------------------------------------------------
__global__ __launch_bounds__(256) void vq_fused(
    const float* __restrict__ zp,           // [4][64][21632]
    const float* __restrict__ b3,           // [64]
    const float* __restrict__ cb,           // [512][64]
    float* __restrict__ out)                // [128][512][169], pre-zeroed
{
    __shared__ float c2s[NEMB];
    __shared__ unsigned long long sh[4][64];

    const int tid  = threadIdx.x;
    const int lane = tid & 63;
    const int wv   = __builtin_amdgcn_readfirstlane(tid >> 6);
    const int p    = blockIdx.x * 64 + lane;       // 338*64 == 21632

#pragma unroll
    for (int i = 0; i < 2; i++) {
        int code = i * 256 + tid;
        const float* c = cb + (size_t)code * EMB;
        float s = 0.f;
#pragma unroll
        for (int j = 0; j < EMB; j += 4) {
            float4 v = *(const float4*)(c + j);
            s = fmaf(v.x, v.x, s); s = fmaf(v.y, v.y, s);
            s = fmaf(v.z, v.z, s); s = fmaf(v.w, v.w, s);
        }
        c2s[code] = s;
    }
    __syncthreads();

    constexpr size_t PSTR = (size_t)EMB * NPIXT;
    float zr[EMB];
    float zz = 0.f;
#pragma unroll
    for (int j = 0; j < EMB; j++) {
        size_t o = (size_t)j * NPIXT + p;
        float v = (zp[o] + zp[PSTR + o]) + (zp[2 * PSTR + o] + zp[3 * PSTR + o]);
        v += b3[j];
        zr[j] = v;
        zz = fmaf(v, v, zz);
    }

    float bestScore = FLT_MAX;
    int   bestIdx   = 0x7fffffff;
    const int base = wv * 128;
    for (int ci = 0; ci < 128; ci++) {
        int code = base + ci;                      // uniform
        const float* c = cb + (size_t)code * EMB;
        float dot = 0.f;
#pragma unroll
        for (int j = 0; j < EMB; j++) dot = fmaf(zr[j], c[j], dot);
        float score = fmaf(-2.f, dot, zz) + c2s[code];
        if (score < bestScore) { bestScore = score; bestIdx = code; }
    }

    unsigned u = __float_as_uint(bestScore);
    u = (bestScore < 0.f) ? ~u : (u | 0x80000000u);
    sh[wv][lane] = ((unsigned long long)u << 32) | (unsigned)bestIdx;
    __syncthreads();

    if (tid < 64) {
        unsigned long long m = sh[0][lane];
        unsigned long long m1 = sh[1][lane]; if (m1 < m) m = m1;
        unsigned long long m2 = sh[2][lane]; if (m2 < m) m = m2;
        unsigned long long m3 = sh[3][lane]; if (m3 < m) m = m3;
        int code = (int)(unsigned)(m & 0xffffffffu);
        int n  = p / HW3;
        int hw = p - n * HW3;
        out[((size_t)n * NEMB + code) * HW3 + hw] = 1.0f;
    }
}

extern "C" void kernel_launch(void* const* d_in, const int* in_sizes, int n_in,
                              void* d_out, int out_size, void* d_ws, size_t ws_size,
                              hipStream_t stream) {
    const float* x  = (const float*)d_in[0];
    const float* w1 = (const float*)d_in[1];
    const float* b1 = (const float*)d_in[2];
    const float* w2 = (const float*)d_in[3];
    const float* b2 = (const float*)d_in[4];
    const float* w3 = (const float*)d_in[5];
    const float* b3 = (const float*)d_in[6];
    const float* cb = (const float*)d_in[7];
    float* out = (float*)d_out;

    // workspace: z1 fp32 NHWC (75.5MB, aliased by z3p after conv2) |
    //            z2 bf16x3 NHWC (25MB) | weight planes (2.6MB)  ~= 103MB
    float* z1  = (float*)d_ws;                       // 18,874,368 f
    float* z3p = z1;                                 // alias (z1 dead at conv3)
    unsigned short* z2a = (unsigned short*)(z1 + (size_t)18874368);
    unsigned short* z2b = z2a + (size_t)4194304;
    unsigned short* z2c = z2b + (size_t)4194304;
    unsigned short* w1a = z2c + (size_t)4194304;
    unsigned short* w1b = w1a + 12288;
    unsigned short* w1c = w1b + 12288;
    unsigned short* w2a = w1c + 12288;
    unsigned short* w2b = w2a + 294912;
    unsigned short* w2c = w2b + 294912;
    unsigned short* w3a = w2c + 294912;
    unsigned short* w3b = w3a + 131072;
    unsigned short* w3c = w3b + 131072;

    hipMemsetAsync(out, 0, (size_t)out_size * sizeof(float), stream);

    wsplit<<<48, 256, 0, stream>>>(w1, w1a, w1b, w1c, 64, 3, 8, 8, 0);
    wsplit<<<1152, 256, 0, stream>>>(w2, w2a, w2b, w2c, 128, 64, 6, 6, 1);
    wsplit<<<512, 256, 0, stream>>>(w3, w3a, w3b, w3c, 64, 128, 4, 4, 1);

    conv1_mfma<<<4608, 256, 0, stream>>>(x, w1a, w1b, w1c, b1, z1);
    conv2_mfma<<<512, 256, 0, stream>>>(z1, w2a, w2b, w2c, b2, z2a, z2b, z2c);
    conv3_mfma<<<1352, 256, 0, stream>>>(z2a, z2b, z2c, w3a, w3b, w3c, z3p);

    vq_fused<<<338, 256, 0, stream>>>(z3p, b3, cb, out);
}